// Round 6
// baseline (3729.358 us; speedup 1.0000x reference)
//
#include <hip/hip_runtime.h>
#include <hip/hip_cooperative_groups.h>
#include <math.h>

namespace cg = cooperative_groups;

#define NIN 64
#define NHID 128
#define NOUT 64
#define NBLK 256     // cooperative grid: <= CU count so occupancy>=1 always suffices
#define TMAX 3       // max tiles (16 nodes each) per block
#define SPRE 516     // fallback k_stepF s_pre stride

typedef __bf16 bf16x8 __attribute__((ext_vector_type(8)));
typedef float  floatx4 __attribute__((ext_vector_type(4)));

__device__ __forceinline__ float sigmoidf(float x){ return 1.0f/(1.0f+expf(-x)); }
__device__ __forceinline__ float b2f_lo(unsigned p){ unsigned b = p<<16; return __uint_as_float(b); }
__device__ __forceinline__ float b2f_hi(unsigned p){ unsigned b = p & 0xffff0000u; return __uint_as_float(b); }
__device__ __forceinline__ unsigned f2pk(float lo, float hi){
  __bf16 a=(__bf16)lo, b=(__bf16)hi;
  unsigned short ua, ub;
  __builtin_memcpy(&ua,&a,2); __builtin_memcpy(&ub,&b,2);
  return (unsigned)ua | ((unsigned)ub<<16);
}

// ---------------- precompute: degree, dinv, CSR ----------------
__global__ void k_deg_init(int* __restrict__ deg, int n){
  int v = blockIdx.x*256 + threadIdx.x;
  if(v<n) deg[v] = 1;
}
__global__ void k_deg_count(const int* __restrict__ dst, int E, int* __restrict__ deg){
  int e = blockIdx.x*256 + threadIdx.x;
  if(e<E) atomicAdd(&deg[dst[e]], 1);
}
__global__ void k_dinv(const int* __restrict__ deg, float* __restrict__ dinv, int n){
  int v = blockIdx.x*256 + threadIdx.x;
  if(v<n) dinv[v] = rsqrtf((float)deg[v]);
}
__global__ __launch_bounds__(1024) void k_scan(const int* __restrict__ deg,
    int* __restrict__ row_ptr, int* __restrict__ fill, int n){
  __shared__ int lds[1024];
  __shared__ int s_carry;
  if(threadIdx.x==0) s_carry=0;
  __syncthreads();
  int nchunk=(n+1023)/1024;
  for(int ch=0; ch<nchunk; ++ch){
    int v = ch*1024 + threadIdx.x;
    int val = (v<n)? (deg[v]-1) : 0;
    lds[threadIdx.x]=val;
    __syncthreads();
    for(int off=1; off<1024; off<<=1){
      int t=(threadIdx.x>=off)? lds[threadIdx.x-off] : 0;
      __syncthreads();
      lds[threadIdx.x]+=t;
      __syncthreads();
    }
    int incl=lds[threadIdx.x];
    int carry=s_carry;
    if(v<n){ row_ptr[v]=carry+incl-val; fill[v]=carry+incl-val; }
    __syncthreads();
    if(threadIdx.x==1023) s_carry=carry+lds[1023];
    __syncthreads();
  }
  if(threadIdx.x==0) row_ptr[n]=s_carry;
}
__global__ void k_fill(const int* __restrict__ src, const int* __restrict__ dst, int E,
                       int* __restrict__ fill, int* __restrict__ ecol){
  int e = blockIdx.x*256 + threadIdx.x;
  if(e<E){
    int d = dst[e];
    int pos = atomicAdd(&fill[d], 1);
    ecol[pos] = src[e];
  }
}

// ---------------- weight prep ----------------
__global__ void k_prep_wb(const float* __restrict__ Wi, const float* __restrict__ Wf,
                          const float* __restrict__ Wo, const float* __restrict__ Wg,
                          __bf16* __restrict__ Wb){
  int idx = blockIdx.x*256 + threadIdx.x;
  if(idx >= 32*6*64*8) return;
  int jj = idx & 7;
  int L  = (idx >> 3) & 63;
  int t  = idx >> 9;
  int kt = t - (t/6)*6, CT = t/6;
  int colj = CT*16 + (L & 15);
  int k    = kt*32 + ((L >> 4) << 3) + jj;
  int gate = colj >> 7, jg = colj & 127;
  const float* W = (gate==0)? Wi : (gate==1)? Wf : (gate==2)? Wo : Wg;
  Wb[idx] = (__bf16)W[jg*192 + k];
}
__global__ void k_prep_w1(const float* __restrict__ W1, float* __restrict__ W1t){
  int idx = blockIdx.x*256 + threadIdx.x;
  if(idx >= 128*256) return;
  int k = idx >> 8, j = idx & 255;
  W1t[idx] = (j<128)? W1[j*256+k] : W1[(j-128)*256+128+k];
}
__global__ void k_prep_wc(const float* __restrict__ Wc, float* __restrict__ Wct){
  int idx = blockIdx.x*256 + threadIdx.x;
  if(idx >= 128*64) return;
  int k = idx/64, j = idx%64;
  Wct[idx] = Wc[j*128+k];
}

// ---------------- init ----------------
__global__ void k_init_coop(unsigned* __restrict__ hpA, unsigned* __restrict__ hpB,
                            float* __restrict__ tmp, __bf16* __restrict__ xs, int NP, int T){
  int i = blockIdx.x*256 + threadIdx.x;
  int szh = (NP+1)*64;
  if(i < szh){ hpA[i]=0u; hpB[i]=0u; }
  if(i < 64) tmp[(size_t)NP*64 + i] = 0.f;
  if(i < T*64){ int t=i>>6, f=i&63; xs[((size_t)t*(NP+1) + NP)*64 + f] = (__bf16)0.f; }
}
__global__ void k_zero_state(float2* __restrict__ cpack, unsigned* __restrict__ hpA, int sz){
  int i = blockIdx.x*256 + threadIdx.x;
  if(i<sz){ cpack[i]=make_float2(0.f,0.f); hpA[i]=0u; }
}

// ---------------- xs = dinv[v] * x, bf16, layout [T][NP+1][64] ----------------
__global__ void k_xscale(const float* __restrict__ x, const float* __restrict__ dinv,
                         __bf16* __restrict__ xs, int n, int NP){
  int i = blockIdx.x*256 + threadIdx.x;
  if(i >= n*64) return;
  int t = blockIdx.y;
  xs[((size_t)t*(NP+1))*64 + i] = (__bf16)(x[(size_t)t*(size_t)n*64 + i]*dinv[i>>6]);
}

// ================= cooperative persistent kernel =================
struct PArgs {
  const __bf16* xs; unsigned* hpA; unsigned* hpB;
  const int* row_ptr; const int* ecol; const float* dinv;
  const __bf16* Wb;
  const float* bi; const float* bff; const float* bo; const float* bg;
  const float* W1t; const float* b1; const float* Wct; const float* bc;
  float* Hio; float* tmp; float* hbuf; float* out;
  int n; int NP; int T; int ntiles;
};

__global__ __launch_bounds__(256,1) void k_persist(PArgs A)
{
  cg::grid_group grid = cg::this_grid();
  __shared__ __align__(16) __bf16 s_a[6*544];
  __shared__ int   s_col[TMAX*1024];
  __shared__ int   s_deg[TMAX*16];
  __shared__ int   s_beg[TMAX*16];
  __shared__ float s_dv [TMAX*16];
  __shared__ float s_buf[16*130];

  const int tid=threadIdx.x, wv=tid>>6, l=tid&63;
  const int l15=l&15, quad=l>>4;
  const int n=A.n, NP=A.NP, T=A.T, ntiles=A.ntiles;

  int myt[TMAX]; int ntl=0;
  for(int tile=blockIdx.x; tile<ntiles; tile+=NBLK){ if(ntl<TMAX) myt[ntl++]=tile; }

  for(int ti=0; ti<ntl; ++ti){
    if(tid<16){
      int v = myt[ti]*16 + tid;
      int beg = (v<n)? A.row_ptr[v]   : 0;
      int end = (v<n)? A.row_ptr[v+1] : 0;
      s_beg[ti*16+tid]=beg; s_deg[ti*16+tid]=end-beg;
      s_dv [ti*16+tid]=(v<n)? A.dinv[v] : 0.f;
    }
  }
  __syncthreads();
  for(int ti=0; ti<ntl; ++ti){
    for(int idx=tid; idx<1024; idx+=256){
      int m=idx>>6, kk=idx&63;
      s_col[ti*1024+idx] = (kk < s_deg[ti*16+m])? A.ecol[s_beg[ti*16+m]+kk] : NP;
    }
  }
  __syncthreads();

  int Kw[TMAX];
  #pragma unroll
  for(int ti=0; ti<TMAX; ++ti) Kw[ti]=0;
  for(int ti=0; ti<ntl; ++ti){
    int d0=s_deg[ti*16+wv*4+0], d1=s_deg[ti*16+wv*4+1];
    int d2=s_deg[ti*16+wv*4+2], d3=s_deg[ti*16+wv*4+3];
    d0=d0>64?64:d0; d1=d1>64?64:d1; d2=d2>64?64:d2; d3=d3>64?64:d3;
    int a=d0>d1?d0:d1, b=d2>d3?d2:d3;
    Kw[ti]=a>b?a:b;
  }

  // B fragments resident in registers for the whole kernel (192 VGPRs)
  bf16x8 wreg[8][6];
  #pragma unroll
  for(int gc=0; gc<8; ++gc){
    int g=gc>>1, c2=gc&1;
    const __bf16* bp = A.Wb + (size_t)((8*g + 2*wv + c2)*6)*512;
    #pragma unroll
    for(int kt=0; kt<6; ++kt)
      wreg[gc][kt] = *(const bf16x8*)(bp + kt*512 + (size_t)l*8);
  }
  float bias_r[4][2];
  #pragma unroll
  for(int c2=0;c2<2;++c2){
    int j=(2*wv+c2)*16+l15;
    bias_r[0][c2]=A.bi[j]; bias_r[1][c2]=A.bff[j]; bias_r[2][c2]=A.bo[j]; bias_r[3][c2]=A.bg[j];
  }
  float c_reg[TMAX*8];
  #pragma unroll
  for(int i=0;i<TMAX*8;++i) c_reg[i]=0.f;

  unsigned* hp_prev=A.hpA; unsigned* hp_cur=A.hpB;

  for(int t=0;t<T;++t){
    const __bf16* xst = A.xs + (size_t)t*(size_t)(NP+1)*64;
    int last = (t==T-1);
    for(int ti=0; ti<ntl; ++ti){
      int v0=myt[ti]*16;
      float ax[4], alo[4], ahi[4];
      #pragma unroll
      for(int i=0;i<4;++i){
        int v=v0+wv*4+i;
        ax[i]=(float)xst[(size_t)v*64+l];
        unsigned p=hp_prev[(size_t)v*64+l];
        alo[i]=b2f_lo(p); ahi[i]=b2f_hi(p);
      }
      const int* cr = &s_col[ti*1024 + (wv*4)*64];
      int K=Kw[ti];
      for(int kk=0; kk<K; ++kk){
        #pragma unroll
        for(int i=0;i<4;++i){
          int u=cr[i*64+kk];
          ax[i]+=(float)xst[(size_t)u*64+l];
          unsigned p=hp_prev[(size_t)u*64+l];
          alo[i]+=b2f_lo(p); ahi[i]+=b2f_hi(p);
        }
      }
      #pragma unroll
      for(int i=0;i<4;++i){            // rare deg>64 overflow
        int mm=ti*16+wv*4+i, d=s_deg[mm];
        if(d>64){
          for(int e2=s_beg[mm]+64; e2<s_beg[mm]+d; ++e2){
            int u=A.ecol[e2];
            ax[i]+=(float)xst[(size_t)u*64+l];
            unsigned p=hp_prev[(size_t)u*64+l];
            alo[i]+=b2f_lo(p); ahi[i]+=b2f_hi(p);
          }
        }
      }
      __syncthreads();   // previous tile's MFMA is done with s_a
      {
        int kt0=l>>5, q0=(l>>3)&3, j0=l&7;
        int L2=2*l; int kt1=2+(L2>>5), q1=(L2>>3)&3, j1=L2&7;
        #pragma unroll
        for(int i=0;i<4;++i){
          int m=wv*4+i;
          float dv=s_dv[ti*16+m];
          s_a[kt0*544+q0*136+m*8+j0]=(__bf16)(dv*ax[i]);
          *(__shared__ unsigned*)&s_a[kt1*544+q1*136+m*8+j1]=f2pk(dv*alo[i],dv*ahi[i]);
        }
      }
      __syncthreads();
      bf16x8 af[6];
      #pragma unroll
      for(int kt=0;kt<6;++kt)
        af[kt]=*(__shared__ bf16x8*)&s_a[kt*544+quad*136+l15*8];
      floatx4 acc[4][2];
      #pragma unroll
      for(int gc=0; gc<8; ++gc){
        int g=gc>>1, c2=gc&1;
        float b=bias_r[g][c2];
        floatx4 a={b,b,b,b};
        #pragma unroll
        for(int kt=0;kt<6;++kt)
          a=__builtin_amdgcn_mfma_f32_16x16x32_bf16(af[kt],wreg[gc][kt],a,0,0,0);
        acc[g][c2]=a;
      }
      #pragma unroll
      for(int c2=0;c2<2;++c2){
        #pragma unroll
        for(int r=0;r<4;++r){
          float I=sigmoidf(acc[0][c2][r]);
          float F=sigmoidf(acc[1][c2][r]);
          float O=sigmoidf(acc[2][c2][r]);
          float G=tanhf  (acc[3][c2][r]);
          int ci=ti*8+c2*4+r;
          float cn=F*c_reg[ci]+I*G;
          c_reg[ci]=cn;
          float hn=O*tanhf(cn);
          int m=quad*4+r;
          float hs=s_dv[ti*16+m]*hn;
          float hs2=__shfl_xor(hs,1,64);
          int j=32*wv+16*c2+l15;
          if((l15&1)==0)
            hp_cur[(size_t)(v0+m)*64+(j>>1)]=f2pk(hs,hs2);  // word w = cols {2w,2w+1}
          if(last) A.hbuf[(size_t)(v0+m)*128+j]=hn;
        }
      }
    }
    __threadfence();
    grid.sync();
    unsigned* tp=hp_prev; hp_prev=hp_cur; hp_cur=tp;
  }

  // ---- head1: Hio = [h@W1a.T | h@W1b.T] ----
  for(int ti=0; ti<ntl; ++ti){
    int v0=myt[ti]*16;
    __syncthreads();
    for(int idx=tid; idx<2048; idx+=256) s_buf[idx]=A.hbuf[(size_t)v0*128+idx];
    __syncthreads();
    float hacc[16];
    #pragma unroll
    for(int m=0;m<16;++m) hacc[m]=0.f;
    for(int k=0;k<128;++k){
      float w=A.W1t[k*256+tid];
      #pragma unroll
      for(int m=0;m<16;++m) hacc[m]=fmaf(w,s_buf[m*128+k],hacc[m]);
    }
    #pragma unroll
    for(int m=0;m<16;++m) A.Hio[(size_t)(v0+m)*256+tid]=hacc[m];
  }
  __threadfence();
  grid.sync();

  // ---- e2n + head2 ----
  for(int ti=0; ti<ntl; ++ti){
    int v0=myt[ti]*16;
    __syncthreads();
    #pragma unroll
    for(int i=0;i<4;++i){
      int m=wv*4+i; int v=v0+m;
      int d=s_deg[ti*16+m];
      float base0=A.Hio[(size_t)v*256+l]+A.b1[l];
      float base1=A.Hio[(size_t)v*256+64+l]+A.b1[64+l];
      float a0=0.f,a1=0.f;
      for(int kk=0;kk<d;++kk){
        int u=(kk<64)? s_col[ti*1024+m*64+kk] : A.ecol[s_beg[ti*16+m]+kk];
        a0+=fmaxf(base0+A.Hio[(size_t)u*256+128+l],0.f);
        a1+=fmaxf(base1+A.Hio[(size_t)u*256+192+l],0.f);
      }
      s_buf[m*130+l]=a0; s_buf[m*130+64+l]=a1;
    }
    __syncthreads();
    #pragma unroll
    for(int i=0;i<4;++i){
      int m=wv*4+i;
      float a=0.f;
      for(int k=0;k<128;++k) a=fmaf(A.Wct[k*64+l],s_buf[m*130+k],a);
      A.tmp[(size_t)(v0+m)*64+l]=s_dv[ti*16+m]*a;
    }
  }
  __threadfence();
  grid.sync();

  // ---- final: out = Anorm @ tmp' + bc ----
  for(int ti=0; ti<ntl; ++ti){
    int v0=myt[ti]*16;
    #pragma unroll
    for(int i=0;i<4;++i){
      int m=wv*4+i; int v=v0+m;
      if(v>=n) continue;
      float a=A.tmp[(size_t)v*64+l];
      int d=s_deg[ti*16+m];
      for(int kk=0;kk<d;++kk){
        int u=(kk<64)? s_col[ti*1024+m*64+kk] : A.ecol[s_beg[ti*16+m]+kk];
        a+=A.tmp[(size_t)u*64+l];
      }
      A.out[(size_t)v*64+l]=s_dv[ti*16+m]*a+A.bc[l];
    }
  }
}

// ================= fallback path (R4, known-good) =================
__global__ __launch_bounds__(256) void k_xagg(const __bf16* __restrict__ xs,
    const int* __restrict__ row_ptr, const int* __restrict__ col,
    const float* __restrict__ dinv, __bf16* __restrict__ xfrag, int n, int NP, int ntiles){
  __shared__ __bf16 s_f[1024];
  int t = blockIdx.y, tile = blockIdx.x;
  const __bf16* xst = xs + (size_t)t*(size_t)(NP+1)*64;
  int tid=threadIdx.x, wv=tid>>6, l=tid&63;
  int v0 = tile*16;
  float a[4]; int e[4], en[4]; float dvv[4];
  #pragma unroll
  for(int i=0;i<4;++i){
    int v = v0 + wv*4 + i;
    bool ok = v<n;
    e[i]  = ok? row_ptr[v]   : 0;
    en[i] = ok? row_ptr[v+1] : 0;
    dvv[i]= ok? dinv[v] : 0.f;
    a[i]  = ok? (float)xst[(size_t)v*64 + l] : 0.f;
  }
  for(;;){
    bool any=false; float val[4];
    #pragma unroll
    for(int i=0;i<4;++i){
      val[i] = 0.f;
      if(e[i]<en[i]){ int u = col[e[i]]; val[i] = (float)xst[(size_t)u*64 + l]; e[i]++; any=true; }
    }
    if(!any) break;
    #pragma unroll
    for(int i=0;i<4;++i) a[i] += val[i];
  }
  #pragma unroll
  for(int i=0;i<4;++i){
    int m = wv*4 + i;
    s_f[(l>>5)*512 + ((l>>3)&3)*128 + m*8 + (l&7)] = (__bf16)(dvv[i]*a[i]);
  }
  __syncthreads();
  const unsigned* sw = (const unsigned*)s_f;
  unsigned* dstp = (unsigned*)(xfrag + ((size_t)t*ntiles + tile)*1024);
  dstp[tid] = sw[tid];
  dstp[256+tid] = sw[256+tid];
}

__global__ __launch_bounds__(256) void k_stepF(const __bf16* __restrict__ xfrag_t,
    const unsigned* __restrict__ hp_prev, unsigned* __restrict__ hp_cur,
    float* __restrict__ hbuf, float2* __restrict__ cpack,
    const int* __restrict__ row_ptr, const int* __restrict__ col,
    const float* __restrict__ dinv, const __bf16* __restrict__ Wb,
    const float* __restrict__ bi, const float* __restrict__ bf_,
    const float* __restrict__ bo, const float* __restrict__ bg, int n, int last){
  __shared__ __align__(16) __bf16 s_a[4*544];
  __shared__ float s_pre[16*SPRE];
  int tid = threadIdx.x, wv = tid>>6, l = tid&63;
  int v0 = blockIdx.x*16;

  const __bf16* xb = xfrag_t + (size_t)blockIdx.x*1024;
  bf16x8 afx0 = *(const bf16x8*)(xb + (size_t)l*8);
  bf16x8 afx1 = *(const bf16x8*)(xb + 512 + (size_t)l*8);

  float a1[4], a2[4]; int e[4], en[4]; float dvv[4];
  #pragma unroll
  for(int i=0;i<4;++i){
    int v = v0 + wv*4 + i;
    bool ok = v<n;
    e[i]  = ok? row_ptr[v]   : 0;
    en[i] = ok? row_ptr[v+1] : 0;
    dvv[i]= ok? dinv[v] : 0.f;
    unsigned p = ok? hp_prev[(size_t)v*64 + l] : 0u;
    a1[i] = b2f_lo(p); a2[i] = b2f_hi(p);
  }
  for(;;){
    bool any=false; unsigned pk[4];
    #pragma unroll
    for(int i=0;i<4;++i){
      pk[i] = 0u;
      if(e[i]<en[i]){ int u = col[e[i]]; pk[i] = hp_prev[(size_t)u*64 + l]; e[i]++; any=true; }
    }
    if(!any) break;
    #pragma unroll
    for(int i=0;i<4;++i){ a1[i] += b2f_lo(pk[i]); a2[i] += b2f_hi(pk[i]); }
  }
  {
    int ktr = l>>5, quad = (l>>3)&3, jj = l&7;
    #pragma unroll
    for(int i=0;i<4;++i){
      int m = wv*4+i;
      s_a[ktr*544     + quad*136 + m*8 + jj] = (__bf16)(dvv[i]*a1[i]);
      s_a[(2+ktr)*544 + quad*136 + m*8 + jj] = (__bf16)(dvv[i]*a2[i]);
    }
  }
  __syncthreads();

  bf16x8 afh[4];
  #pragma unroll
  for(int kt=0;kt<4;++kt)
    afh[kt] = *(__shared__ bf16x8*)&s_a[kt*544 + (l>>4)*136 + (l&15)*8];
  const float* bsel = (wv==0)? bi : (wv==1)? bf_ : (wv==2)? bo : bg;
  #pragma unroll
  for(int ctl=0; ctl<8; ++ctl){
    int CT = wv*8 + ctl;
    float b = bsel[ctl*16 + (l&15)];
    floatx4 acc = {b,b,b,b};
    const __bf16* bp = Wb + (size_t)(CT*6)*512;
    acc = __builtin_amdgcn_mfma_f32_16x16x32_bf16(afx0,   *(const bf16x8*)(bp        + (size_t)l*8), acc, 0,0,0);
    acc = __builtin_amdgcn_mfma_f32_16x16x32_bf16(afx1,   *(const bf16x8*)(bp + 512  + (size_t)l*8), acc, 0,0,0);
    acc = __builtin_amdgcn_mfma_f32_16x16x32_bf16(afh[0], *(const bf16x8*)(bp + 1024 + (size_t)l*8), acc, 0,0,0);
    acc = __builtin_amdgcn_mfma_f32_16x16x32_bf16(afh[1], *(const bf16x8*)(bp + 1536 + (size_t)l*8), acc, 0,0,0);
    acc = __builtin_amdgcn_mfma_f32_16x16x32_bf16(afh[2], *(const bf16x8*)(bp + 2048 + (size_t)l*8), acc, 0,0,0);
    acc = __builtin_amdgcn_mfma_f32_16x16x32_bf16(afh[3], *(const bf16x8*)(bp + 2560 + (size_t)l*8), acc, 0,0,0);
    int j = CT*16 + (l&15);
    int mrow = ((l>>4))*4;
    #pragma unroll
    for(int r=0;r<4;++r) s_pre[(mrow+r)*SPRE + j] = acc[r];
  }
  __syncthreads();

  #pragma unroll
  for(int it=0; it<4; ++it){
    int m = it*4 + (tid>>6);
    int v = v0 + m;
    if(v >= n) continue;
    float dv = dinv[v];
    const float* row = &s_pre[m*SPRE];
    float i1 = sigmoidf(row[l]);
    float f1 = sigmoidf(row[128+l]);
    float o1 = sigmoidf(row[256+l]);
    float g1 = tanhf  (row[384+l]);
    float i2 = sigmoidf(row[64+l]);
    float f2 = sigmoidf(row[192+l]);
    float o2 = sigmoidf(row[320+l]);
    float g2 = tanhf  (row[448+l]);
    size_t off = (size_t)v*64 + l;
    float2 cc = cpack[off];
    float c1 = f1*cc.x + i1*g1;
    float c2 = f2*cc.y + i2*g2;
    cpack[off] = make_float2(c1,c2);
    float h1 = o1*tanhf(c1), h2 = o2*tanhf(c2);
    hp_cur[off] = f2pk(dv*h1, dv*h2);
    if(last){
      hbuf[(size_t)v*NHID + l]      = h1;
      hbuf[(size_t)v*NHID + 64 + l] = h2;
    }
  }
}

__global__ __launch_bounds__(256) void k_head1(const float* __restrict__ h,
    const float* __restrict__ W1t, float* __restrict__ Hio, int n){
  __shared__ float s_h[16][NHID];
  int v0 = blockIdx.x*16;
  for(int i=threadIdx.x; i<16*NHID; i+=256){
    int m = i/NHID, k = i - m*NHID;
    int v = v0 + m;
    s_h[m][k] = (v<n)? h[(size_t)v*NHID + k] : 0.0f;
  }
  __syncthreads();
  int j = threadIdx.x;
  float acc[16];
  #pragma unroll
  for(int m=0;m<16;++m) acc[m]=0.f;
  for(int k=0;k<NHID;++k){
    float w = W1t[k*256 + j];
    #pragma unroll
    for(int m=0;m<16;++m) acc[m] = fmaf(w, s_h[m][k], acc[m]);
  }
  for(int m=0;m<16;++m){
    int v = v0 + m;
    if(v >= n) break;
    Hio[(size_t)v*256 + j] = acc[m];
  }
}
__global__ __launch_bounds__(256) void k_e2n(const float* __restrict__ Hio,
    const int* __restrict__ row_ptr, const int* __restrict__ col,
    const float* __restrict__ b1, float* __restrict__ nodes, int n){
  int wv = threadIdx.x >> 6, lane = threadIdx.x & 63;
  int v = blockIdx.x*4 + wv;
  if(v >= n) return;
  float base0 = Hio[(size_t)v*256 + lane]      + b1[lane];
  float base1 = Hio[(size_t)v*256 + 64 + lane] + b1[64+lane];
  float a0=0.f, a1=0.f;
  int beg=row_ptr[v], end=row_ptr[v+1];
  for(int e=beg; e<end; ++e){
    int u = col[e];
    float t0 = base0 + Hio[(size_t)u*256 + 128 + lane];
    float t1 = base1 + Hio[(size_t)u*256 + 192 + lane];
    a0 += fmaxf(t0, 0.0f);
    a1 += fmaxf(t1, 0.0f);
  }
  nodes[(size_t)v*NHID + lane]      = a0;
  nodes[(size_t)v*NHID + 64 + lane] = a1;
}
__global__ __launch_bounds__(64) void k_head2(const float* __restrict__ nodes,
    const float* __restrict__ Wct, float* __restrict__ tmp, int n){
  __shared__ float s_n[16][NHID];
  int v0 = blockIdx.x*16;
  for(int i=threadIdx.x; i<16*NHID; i+=64){
    int m = i/NHID, k = i - m*NHID;
    int v = v0 + m;
    s_n[m][k] = (v<n)? nodes[(size_t)v*NHID + k] : 0.0f;
  }
  __syncthreads();
  int j = threadIdx.x;
  float acc[16];
  #pragma unroll
  for(int m=0;m<16;++m) acc[m]=0.f;
  for(int k=0;k<NHID;++k){
    float w = Wct[k*64 + j];
    #pragma unroll
    for(int m=0;m<16;++m) acc[m] = fmaf(w, s_n[m][k], acc[m]);
  }
  for(int m=0;m<16;++m){
    int v = v0 + m;
    if(v >= n) break;
    tmp[(size_t)v*64 + j] = acc[m];
  }
}
__global__ __launch_bounds__(256) void k_final(const float* __restrict__ tmp,
    const int* __restrict__ row_ptr, const int* __restrict__ col,
    const float* __restrict__ dinv, const float* __restrict__ bc,
    float* __restrict__ out, int n){
  int wv = threadIdx.x >> 6, lane = threadIdx.x & 63;
  int v = blockIdx.x*4 + wv;
  if(v >= n) return;
  float dv = dinv[v];
  float acc = dv*dv*tmp[(size_t)v*64 + lane];
  int beg=row_ptr[v], end=row_ptr[v+1];
  for(int e=beg; e<end; ++e){
    int u = col[e];
    acc = fmaf(dv*dinv[u], tmp[(size_t)u*64 + lane], acc);
  }
  out[(size_t)v*64 + lane] = acc + bc[lane];
}

extern "C" void kernel_launch(void* const* d_in, const int* in_sizes, int n_in,
                              void* d_out, int out_size, void* d_ws, size_t ws_size,
                              hipStream_t stream) {
  (void)n_in; (void)ws_size;
  const float* x  = (const float*)d_in[0];
  const int*   ei = (const int*)d_in[1];
  const float* Wi = (const float*)d_in[4];  const float* bi  = (const float*)d_in[5];
  const float* Wf = (const float*)d_in[6];  const float* bf_ = (const float*)d_in[7];
  const float* Wo = (const float*)d_in[8];  const float* bo  = (const float*)d_in[9];
  const float* Wg = (const float*)d_in[10]; const float* bg  = (const float*)d_in[11];
  const float* W1 = (const float*)d_in[12]; const float* b1  = (const float*)d_in[13];
  const float* Wc = (const float*)d_in[14]; const float* bc  = (const float*)d_in[15];
  float* out = (float*)d_out;

  const int E = in_sizes[2];
  const int n = out_size / NOUT;
  const int T = in_sizes[0] / (n * NIN);
  const int ntiles = (n + 15)/16;
  const int NP = ntiles*16;
  const int* srcl = ei;
  const int* dstl = ei + E;

  char* p = (char*)d_ws;
  auto alloc = [&](size_t bytes){ char* r = p; p += ((bytes + 255)/256)*256; return r; };
  int*      deg     = (int*)     alloc((size_t)n*4);
  float*    dinv    = (float*)   alloc((size_t)n*4);
  int*      row_ptr = (int*)     alloc((size_t)(n+1)*4);
  int*      fill    = (int*)     alloc((size_t)n*4);
  int*      ecol    = (int*)     alloc((size_t)E*4);
  __bf16*   Wb      = (__bf16*)  alloc((size_t)32*6*64*8*2);
  float*    W1t     = (float*)   alloc((size_t)128*256*4);
  float*    Wct     = (float*)   alloc((size_t)128*64*4);
  __bf16*   xs      = (__bf16*)  alloc((size_t)T*(NP+1)*64*2);
  unsigned* hpA     = (unsigned*)alloc((size_t)(NP+1)*64*4);
  unsigned* hpB     = (unsigned*)alloc((size_t)(NP+1)*64*4);
  float*    Hio     = (float*)   alloc((size_t)NP*256*4);
  float*    tmp     = (float*)   alloc((size_t)(NP+1)*64*4);
  float*    hbuf    = (float*)   alloc((size_t)NP*128*4);
  // fallback-only buffers
  __bf16*   xfragF  = (__bf16*)  alloc((size_t)T*ntiles*1024*2);
  float2*   cpackF  = (float2*)  alloc((size_t)n*64*8);
  float*    nodesF  = (float*)   alloc((size_t)n*NHID*4);

  int gn = (n+255)/256;
  int gE = (E+255)/256;

  k_deg_init <<<gn, 256, 0, stream>>>(deg, n);
  k_deg_count<<<gE, 256, 0, stream>>>(dstl, E, deg);
  k_dinv     <<<gn, 256, 0, stream>>>(deg, dinv, n);
  k_scan     <<<1, 1024, 0, stream>>>(deg, row_ptr, fill, n);
  k_fill     <<<gE, 256, 0, stream>>>(srcl, dstl, E, fill, ecol);

  k_prep_wb<<<(32*6*64*8+255)/256, 256, 0, stream>>>(Wi, Wf, Wo, Wg, Wb);
  k_prep_w1<<<(128*256+255)/256, 256, 0, stream>>>(W1, W1t);
  k_prep_wc<<<(128*64+255)/256, 256, 0, stream>>>(Wc, Wct);

  k_xscale<<<dim3((n*64+255)/256, T), 256, 0, stream>>>(x, dinv, xs, n, NP);

  // --- capture-safe, deterministic cooperative-launch feasibility check ---
  int dev=0; hipGetDevice(&dev);
  int coopAttr=0; hipDeviceGetAttribute(&coopAttr, hipDeviceAttributeCooperativeLaunch, dev);
  int nCU=0;      hipDeviceGetAttribute(&nCU, hipDeviceAttributeMultiprocessorCount, dev);
  int maxAct=0;   hipOccupancyMaxActiveBlocksPerMultiprocessor(&maxAct, k_persist, 256, 0);
  bool coop = (coopAttr!=0) && (nCU>0) && ((long)maxAct*(long)nCU >= (long)NBLK)
              && (ntiles <= TMAX*NBLK);

  if(coop){
    k_init_coop<<<((NP+1)*64+255)/256, 256, 0, stream>>>(hpA, hpB, tmp, xs, NP, T);
    PArgs pa;
    pa.xs=xs; pa.hpA=hpA; pa.hpB=hpB; pa.row_ptr=row_ptr; pa.ecol=ecol; pa.dinv=dinv;
    pa.Wb=Wb; pa.bi=bi; pa.bff=bf_; pa.bo=bo; pa.bg=bg;
    pa.W1t=W1t; pa.b1=b1; pa.Wct=Wct; pa.bc=bc;
    pa.Hio=Hio; pa.tmp=tmp; pa.hbuf=hbuf; pa.out=out;
    pa.n=n; pa.NP=NP; pa.T=T; pa.ntiles=ntiles;
    void* args[] = { (void*)&pa };
    hipError_t err = hipLaunchCooperativeKernel(k_persist, dim3(NBLK), dim3(256), args, 0u, stream);
    if(err != hipSuccess) coop = false;
  }
  if(!coop){
    // known-good R4 path
    k_zero_state<<<((n*64)+255)/256, 256, 0, stream>>>(cpackF, hpA, n*64);
    k_xagg<<<dim3(ntiles, T), 256, 0, stream>>>(xs, row_ptr, ecol, dinv, xfragF, n, NP, ntiles);
    for(int t=0; t<T; ++t){
      const __bf16* xft = xfragF + ((size_t)t*ntiles)*1024;
      const unsigned* hp = (t & 1)? hpB : hpA;
      unsigned*       hc = (t & 1)? hpA : hpB;
      k_stepF<<<ntiles, 256, 0, stream>>>(xft, hp, hc, hbuf, cpackF, row_ptr, ecol, dinv,
                                          Wb, bi, bf_, bo, bg, n, (t==T-1)?1:0);
    }
    k_head1<<<ntiles, 256, 0, stream>>>(hbuf, W1t, Hio, n);
    k_e2n  <<<(n+3)/4, 256, 0, stream>>>(Hio, row_ptr, ecol, b1, nodesF, n);
    k_head2<<<(n+15)/16, 64, 0, stream>>>(nodesF, Wct, tmp, n);
    k_final<<<(n+3)/4, 256, 0, stream>>>(tmp, row_ptr, ecol, dinv, bc, out, n);
  }
}

// Round 7
// 1635.636 us; speedup vs baseline: 2.2801x; 2.2801x over previous
//
#include <hip/hip_runtime.h>
#include <math.h>

#define NIN 64
#define NHID 128
#define NOUT 64

typedef __bf16 bf16x8 __attribute__((ext_vector_type(8)));
typedef float  floatx4 __attribute__((ext_vector_type(4)));

__device__ __forceinline__ float sigmoidf(float x){ return 1.0f/(1.0f+expf(-x)); }
__device__ __forceinline__ float b2f_lo(unsigned p){ unsigned b = p<<16; return __uint_as_float(b); }
__device__ __forceinline__ float b2f_hi(unsigned p){ unsigned b = p & 0xffff0000u; return __uint_as_float(b); }
__device__ __forceinline__ unsigned f2pk(float lo, float hi){
  __bf16 a=(__bf16)lo, b=(__bf16)hi;
  unsigned short ua, ub;
  __builtin_memcpy(&ua,&a,2); __builtin_memcpy(&ub,&b,2);
  return (unsigned)ua | ((unsigned)ub<<16);
}

// ---------------- precompute: degree, dinv, CSR ----------------
__global__ void k_deg_init(int* __restrict__ deg, int n){
  int v = blockIdx.x*256 + threadIdx.x;
  if(v<n) deg[v] = 1;
}
__global__ void k_deg_count(const int* __restrict__ dst, int E, int* __restrict__ deg){
  int e = blockIdx.x*256 + threadIdx.x;
  if(e<E) atomicAdd(&deg[dst[e]], 1);
}
__global__ void k_dinv(const int* __restrict__ deg, float* __restrict__ dinv, int n){
  int v = blockIdx.x*256 + threadIdx.x;
  if(v<n) dinv[v] = rsqrtf((float)deg[v]);
}
__global__ __launch_bounds__(1024) void k_scan(const int* __restrict__ deg,
    int* __restrict__ row_ptr, int* __restrict__ fill, int n){
  __shared__ int lds[1024];
  __shared__ int s_carry;
  if(threadIdx.x==0) s_carry=0;
  __syncthreads();
  int nchunk=(n+1023)/1024;
  for(int ch=0; ch<nchunk; ++ch){
    int v = ch*1024 + threadIdx.x;
    int val = (v<n)? (deg[v]-1) : 0;
    lds[threadIdx.x]=val;
    __syncthreads();
    for(int off=1; off<1024; off<<=1){
      int t=(threadIdx.x>=off)? lds[threadIdx.x-off] : 0;
      __syncthreads();
      lds[threadIdx.x]+=t;
      __syncthreads();
    }
    int incl=lds[threadIdx.x];
    int carry=s_carry;
    if(v<n){ row_ptr[v]=carry+incl-val; fill[v]=carry+incl-val; }
    __syncthreads();
    if(threadIdx.x==1023) s_carry=carry+lds[1023];
    __syncthreads();
  }
  if(threadIdx.x==0) row_ptr[n]=s_carry;
}
__global__ void k_fill(const int* __restrict__ src, const int* __restrict__ dst, int E,
                       int* __restrict__ fill, int* __restrict__ ecol){
  int e = blockIdx.x*256 + threadIdx.x;
  if(e<E){
    int d = dst[e];
    int pos = atomicAdd(&fill[d], 1);
    ecol[pos] = src[e];
  }
}

// ---------------- weight prep ----------------
__global__ void k_prep_wb(const float* __restrict__ Wi, const float* __restrict__ Wf,
                          const float* __restrict__ Wo, const float* __restrict__ Wg,
                          __bf16* __restrict__ Wb){
  int idx = blockIdx.x*256 + threadIdx.x;
  if(idx >= 32*6*64*8) return;
  int jj = idx & 7;
  int L  = (idx >> 3) & 63;
  int t  = idx >> 9;
  int kt = t - (t/6)*6, CT = t/6;
  int colj = CT*16 + (L & 15);
  int k    = kt*32 + ((L >> 4) << 3) + jj;
  int gate = colj >> 7, jg = colj & 127;
  const float* W = (gate==0)? Wi : (gate==1)? Wf : (gate==2)? Wo : Wg;
  Wb[idx] = (__bf16)W[jg*192 + k];
}
__global__ void k_prep_w1(const float* __restrict__ W1, float* __restrict__ W1t){
  int idx = blockIdx.x*256 + threadIdx.x;
  if(idx >= 128*256) return;
  int k = idx >> 8, j = idx & 255;
  W1t[idx] = (j<128)? W1[j*256+k] : W1[(j-128)*256+128+k];
}
__global__ void k_prep_wc(const float* __restrict__ Wc, float* __restrict__ Wct){
  int idx = blockIdx.x*256 + threadIdx.x;
  if(idx >= 128*64) return;
  int k = idx/64, j = idx%64;
  Wct[idx] = Wc[j*128+k];
}

// ---------------- init: zero h (both bufs incl ghost row), c, xs ghost row ----
__global__ void k_init(unsigned* __restrict__ hpA, unsigned* __restrict__ hpB,
                       float* __restrict__ cbuf, __bf16* __restrict__ xs,
                       int NP, int T){
  int i = blockIdx.x*256 + threadIdx.x;
  if(i < (NP+1)*64){ hpA[i]=0u; hpB[i]=0u; }
  if(i < NP*128) cbuf[i]=0.f;
  if(i < T*64){ int t=i>>6, f=i&63; xs[((size_t)t*(NP+1) + NP)*64 + f] = (__bf16)0.f; }
}

// ---------------- xs = dinv[v] * x, bf16, layout [T][NP+1][64] ----------------
__global__ void k_xscale(const float* __restrict__ x, const float* __restrict__ dinv,
                         __bf16* __restrict__ xs, int n, int NP){
  int i = blockIdx.x*256 + threadIdx.x;
  if(i >= n*64) return;
  int t = blockIdx.y;
  xs[((size_t)t*(NP+1))*64 + i] = (__bf16)(x[(size_t)t*(size_t)n*64 + i]*dinv[i>>6]);
}

// ---------------- fused step: 512 thr = 8 waves, 16 nodes/block -----------
// wave wv gathers nodes {2wv, 2wv+1}; MFMA: wave wv computes cols 16wv..16wv+15
// of ALL 4 gates (CT = 8g+wv); pointwise fully in registers; c in global.
__global__ __launch_bounds__(512,5) void k_step(
    const __bf16* __restrict__ xst,        // [NP+1][64] slab for step t
    const unsigned* __restrict__ hp_prev,  // [NP+1][64]
    unsigned* __restrict__ hp_cur,
    float* __restrict__ cbuf,              // [NP][128]
    float* __restrict__ hbuf,              // [NP][128] (written on last step)
    const int* __restrict__ row_ptr, const int* __restrict__ ecol,
    const float* __restrict__ dinv, const __bf16* __restrict__ Wb,
    const float* __restrict__ bi, const float* __restrict__ bf_,
    const float* __restrict__ bo, const float* __restrict__ bg,
    int n, int NP, int last)
{
  __shared__ __align__(16) __bf16 s_a[6*544];
  __shared__ int   s_col[1024];
  __shared__ int   s_deg[16];
  __shared__ int   s_beg[16];
  __shared__ float s_dv[16];
  const int tid=threadIdx.x, wv=tid>>6, l=tid&63;
  const int l15=l&15, quad=l>>4;
  const int v0=blockIdx.x*16;

  if(tid<16){
    int v=v0+tid;
    int beg=(v<n)? row_ptr[v]:0, end=(v<n)? row_ptr[v+1]:0;
    s_beg[tid]=beg; s_deg[tid]=end-beg;
    s_dv[tid]=(v<n)? dinv[v]:0.f;
  }
  __syncthreads();
  for(int idx=tid; idx<1024; idx+=512){
    int m=idx>>6, kk=idx&63;
    s_col[idx]=(kk<s_deg[m])? ecol[s_beg[m]+kk] : NP;   // pad -> zero ghost row
  }
  __syncthreads();

  // ---- phase 1: gather (self + ELL neighbors), 2 nodes per wave ----
  float ax[2], alo[2], ahi[2];
  int K;
  {
    int d0=s_deg[2*wv], d1=s_deg[2*wv+1];
    d0=d0>64?64:d0; d1=d1>64?64:d1;
    K=d0>d1?d0:d1;
  }
  #pragma unroll
  for(int i=0;i<2;++i){
    int v=v0+2*wv+i;
    ax[i]=(float)xst[(size_t)v*64+l];
    unsigned p=hp_prev[(size_t)v*64+l];
    alo[i]=b2f_lo(p); ahi[i]=b2f_hi(p);
  }
  const int* cr=&s_col[(2*wv)*64];
  #pragma unroll 2
  for(int kk=0;kk<K;++kk){
    int u0=cr[kk], u1=cr[64+kk];
    float    x0=(float)xst[(size_t)u0*64+l];
    unsigned p0=hp_prev[(size_t)u0*64+l];
    float    x1=(float)xst[(size_t)u1*64+l];
    unsigned p1=hp_prev[(size_t)u1*64+l];
    ax[0]+=x0; alo[0]+=b2f_lo(p0); ahi[0]+=b2f_hi(p0);
    ax[1]+=x1; alo[1]+=b2f_lo(p1); ahi[1]+=b2f_hi(p1);
  }
  #pragma unroll
  for(int i=0;i<2;++i){              // rare deg>64 overflow
    int m=2*wv+i, d=s_deg[m];
    if(d>64){
      for(int e2=s_beg[m]+64;e2<s_beg[m]+d;++e2){
        int u=ecol[e2];
        ax[i]+=(float)xst[(size_t)u*64+l];
        unsigned p=hp_prev[(size_t)u*64+l];
        alo[i]+=b2f_lo(p); ahi[i]+=b2f_hi(p);
      }
    }
  }
  {
    int kt0=l>>5, q0=(l>>3)&3, j0=l&7;
    int L2=2*l, kt1=2+(L2>>5), q1=(L2>>3)&3, j1=L2&7;
    #pragma unroll
    for(int i=0;i<2;++i){
      int m=2*wv+i; float dv=s_dv[m];
      s_a[kt0*544+q0*136+m*8+j0]=(__bf16)(dv*ax[i]);
      *(__shared__ unsigned*)&s_a[kt1*544+q1*136+m*8+j1]=f2pk(dv*alo[i],dv*ahi[i]);
    }
  }
  __syncthreads();

  // ---- phase 2: MFMA; wave wv: CT = 8g+wv per gate g ----
  bf16x8 af[6];
  #pragma unroll
  for(int kt=0;kt<6;++kt)
    af[kt]=*(__shared__ bf16x8*)&s_a[kt*544+quad*136+l15*8];
  const int jg=16*wv+l15;
  floatx4 acc[4];
  {
    const float* bs0=bi; const float* bs1=bf_; const float* bs2=bo; const float* bs3=bg;
    #pragma unroll
    for(int g=0;g<4;++g){
      const float* bsel = (g==0)? bs0 : (g==1)? bs1 : (g==2)? bs2 : bs3;
      float b=bsel[jg];
      floatx4 a={b,b,b,b};
      const __bf16* bp=Wb + (size_t)((8*g+wv)*6)*512 + (size_t)l*8;
      #pragma unroll
      for(int kt=0;kt<6;++kt)
        a=__builtin_amdgcn_mfma_f32_16x16x32_bf16(af[kt],*(const bf16x8*)(bp+kt*512),a,0,0,0);
      acc[g]=a;
    }
  }

  // ---- phase 3: LSTM pointwise in registers ----
  #pragma unroll
  for(int r=0;r<4;++r){
    int m=quad*4+r, v=v0+m;
    float I=sigmoidf(acc[0][r]);
    float F=sigmoidf(acc[1][r]);
    float O=sigmoidf(acc[2][r]);
    float G=tanhf  (acc[3][r]);
    size_t coff=(size_t)v*128+jg;
    float cn=F*cbuf[coff]+I*G;
    cbuf[coff]=cn;
    float hn=O*tanhf(cn);
    float hs=s_dv[m]*hn;
    float hs2=__shfl_xor(hs,1,64);
    if((l15&1)==0)
      hp_cur[(size_t)v*64+(jg>>1)]=f2pk(hs,hs2);   // word w = cols {2w,2w+1}
    if(last) hbuf[coff]=hn;
  }
}

// ---------------- head (R4-verified chain) ----------------
__global__ __launch_bounds__(256) void k_head1(const float* __restrict__ h,
    const float* __restrict__ W1t, float* __restrict__ Hio, int n){
  __shared__ float s_h[16][NHID];
  int v0 = blockIdx.x*16;
  for(int i=threadIdx.x; i<16*NHID; i+=256){
    int m = i/NHID, k = i - m*NHID;
    int v = v0 + m;
    s_h[m][k] = (v<n)? h[(size_t)v*NHID + k] : 0.0f;
  }
  __syncthreads();
  int j = threadIdx.x;
  float acc[16];
  #pragma unroll
  for(int m=0;m<16;++m) acc[m]=0.f;
  for(int k=0;k<NHID;++k){
    float w = W1t[k*256 + j];
    #pragma unroll
    for(int m=0;m<16;++m) acc[m] = fmaf(w, s_h[m][k], acc[m]);
  }
  for(int m=0;m<16;++m){
    int v = v0 + m;
    if(v >= n) break;
    Hio[(size_t)v*256 + j] = acc[m];
  }
}
__global__ __launch_bounds__(256) void k_e2n(const float* __restrict__ Hio,
    const int* __restrict__ row_ptr, const int* __restrict__ col,
    const float* __restrict__ b1, float* __restrict__ nodes, int n){
  int wv = threadIdx.x >> 6, lane = threadIdx.x & 63;
  int v = blockIdx.x*4 + wv;
  if(v >= n) return;
  float base0 = Hio[(size_t)v*256 + lane]      + b1[lane];
  float base1 = Hio[(size_t)v*256 + 64 + lane] + b1[64+lane];
  float a0=0.f, a1=0.f;
  int beg=row_ptr[v], end=row_ptr[v+1];
  for(int e=beg; e<end; ++e){
    int u = col[e];
    float t0 = base0 + Hio[(size_t)u*256 + 128 + lane];
    float t1 = base1 + Hio[(size_t)u*256 + 192 + lane];
    a0 += fmaxf(t0, 0.0f);
    a1 += fmaxf(t1, 0.0f);
  }
  nodes[(size_t)v*NHID + lane]      = a0;
  nodes[(size_t)v*NHID + 64 + lane] = a1;
}
__global__ __launch_bounds__(64) void k_head2(const float* __restrict__ nodes,
    const float* __restrict__ Wct, float* __restrict__ tmp, int n){
  __shared__ float s_n[16][NHID];
  int v0 = blockIdx.x*16;
  for(int i=threadIdx.x; i<16*NHID; i+=64){
    int m = i/NHID, k = i - m*NHID;
    int v = v0 + m;
    s_n[m][k] = (v<n)? nodes[(size_t)v*NHID + k] : 0.0f;
  }
  __syncthreads();
  int j = threadIdx.x;
  float acc[16];
  #pragma unroll
  for(int m=0;m<16;++m) acc[m]=0.f;
  for(int k=0;k<NHID;++k){
    float w = Wct[k*64 + j];
    #pragma unroll
    for(int m=0;m<16;++m) acc[m] = fmaf(w, s_n[m][k], acc[m]);
  }
  for(int m=0;m<16;++m){
    int v = v0 + m;
    if(v >= n) break;
    tmp[(size_t)v*64 + j] = acc[m];
  }
}
__global__ __launch_bounds__(256) void k_final(const float* __restrict__ tmp,
    const int* __restrict__ row_ptr, const int* __restrict__ col,
    const float* __restrict__ dinv, const float* __restrict__ bc,
    float* __restrict__ out, int n){
  int wv = threadIdx.x >> 6, lane = threadIdx.x & 63;
  int v = blockIdx.x*4 + wv;
  if(v >= n) return;
  float dv = dinv[v];
  float acc = dv*dv*tmp[(size_t)v*64 + lane];
  int beg=row_ptr[v], end=row_ptr[v+1];
  for(int e=beg; e<end; ++e){
    int u = col[e];
    acc = fmaf(dv*dinv[u], tmp[(size_t)u*64 + lane], acc);
  }
  out[(size_t)v*64 + lane] = acc + bc[lane];
}

extern "C" void kernel_launch(void* const* d_in, const int* in_sizes, int n_in,
                              void* d_out, int out_size, void* d_ws, size_t ws_size,
                              hipStream_t stream) {
  (void)n_in; (void)ws_size;
  const float* x  = (const float*)d_in[0];
  const int*   ei = (const int*)d_in[1];
  const float* Wi = (const float*)d_in[4];  const float* bi  = (const float*)d_in[5];
  const float* Wf = (const float*)d_in[6];  const float* bf_ = (const float*)d_in[7];
  const float* Wo = (const float*)d_in[8];  const float* bo  = (const float*)d_in[9];
  const float* Wg = (const float*)d_in[10]; const float* bg  = (const float*)d_in[11];
  const float* W1 = (const float*)d_in[12]; const float* b1  = (const float*)d_in[13];
  const float* Wc = (const float*)d_in[14]; const float* bc  = (const float*)d_in[15];
  float* out = (float*)d_out;

  const int E = in_sizes[2];
  const int n = out_size / NOUT;
  const int T = in_sizes[0] / (n * NIN);
  const int ntiles = (n + 15)/16;
  const int NP = ntiles*16;
  const int* srcl = ei;
  const int* dstl = ei + E;

  char* p = (char*)d_ws;
  auto alloc = [&](size_t bytes){ char* r = p; p += ((bytes + 255)/256)*256; return r; };
  int*      deg     = (int*)     alloc((size_t)n*4);
  float*    dinv    = (float*)   alloc((size_t)n*4);
  int*      row_ptr = (int*)     alloc((size_t)(n+1)*4);
  int*      fill    = (int*)     alloc((size_t)n*4);
  int*      ecol    = (int*)     alloc((size_t)E*4);
  __bf16*   Wb      = (__bf16*)  alloc((size_t)32*6*64*8*2);
  float*    W1t     = (float*)   alloc((size_t)128*256*4);
  float*    Wct     = (float*)   alloc((size_t)128*64*4);
  __bf16*   xs      = (__bf16*)  alloc((size_t)T*(NP+1)*64*2);
  unsigned* hpA     = (unsigned*)alloc((size_t)(NP+1)*64*4);
  unsigned* hpB     = (unsigned*)alloc((size_t)(NP+1)*64*4);
  float*    cbuf    = (float*)   alloc((size_t)NP*128*4);
  float*    hbuf    = (float*)   alloc((size_t)NP*128*4);
  float*    Hio     = (float*)   alloc((size_t)NP*256*4);
  float*    nodes   = (float*)   alloc((size_t)n*NHID*4);
  float*    tmp     = (float*)   alloc((size_t)NP*64*4);

  int gn = (n+255)/256;
  int gE = (E+255)/256;

  k_deg_init <<<gn, 256, 0, stream>>>(deg, n);
  k_deg_count<<<gE, 256, 0, stream>>>(dstl, E, deg);
  k_dinv     <<<gn, 256, 0, stream>>>(deg, dinv, n);
  k_scan     <<<1, 1024, 0, stream>>>(deg, row_ptr, fill, n);
  k_fill     <<<gE, 256, 0, stream>>>(srcl, dstl, E, fill, ecol);

  k_prep_wb<<<(32*6*64*8+255)/256, 256, 0, stream>>>(Wi, Wf, Wo, Wg, Wb);
  k_prep_w1<<<(128*256+255)/256, 256, 0, stream>>>(W1, W1t);
  k_prep_wc<<<(128*64+255)/256, 256, 0, stream>>>(Wc, Wct);

  k_init<<<((NP*128)+255)/256, 256, 0, stream>>>(hpA, hpB, cbuf, xs, NP, T);
  k_xscale<<<dim3((n*64+255)/256, T), 256, 0, stream>>>(x, dinv, xs, n, NP);

  for(int t=0; t<T; ++t){
    const __bf16* xst = xs + (size_t)t*(size_t)(NP+1)*64;
    const unsigned* hp = (t & 1)? hpB : hpA;
    unsigned*       hc = (t & 1)? hpA : hpB;
    k_step<<<ntiles, 512, 0, stream>>>(xst, hp, hc, cbuf, hbuf, row_ptr, ecol, dinv,
                                       Wb, bi, bf_, bo, bg, n, NP, (t==T-1)?1:0);
  }

  k_head1<<<ntiles, 256, 0, stream>>>(hbuf, W1t, Hio, n);
  k_e2n  <<<(n+3)/4, 256, 0, stream>>>(Hio, row_ptr, ecol, b1, nodes, n);
  k_head2<<<(n+15)/16, 64, 0, stream>>>(nodes, Wct, tmp, n);
  k_final<<<(n+3)/4, 256, 0, stream>>>(tmp, row_ptr, ecol, dinv, bc, out, n);
}